// Round 5
// baseline (296.878 us; speedup 1.0000x reference)
//
#include <hip/hip_runtime.h>
#include <hip/hip_bf16.h>

// GCN decoder, 4 dispatches:
//  1) prep_t0_k: blocks 0-255 compute msg0 = lat@W0+b0; blocks 256-415 transpose
//     W1/W2/Wout to bf16 [fo][k]; blocks 416+ stream-convert adj fp32 -> bf16
//     (pure coalesced copy at streaming BW, ~6 TB/s).
//  2-4) agg_k<MODE>: h = relu(adj_bf16 @ msg) + fused epilogue GEMM.
//       MODE=0: epilogue = next transform (msg_out). MODE=1: output proj * mask.
// XCD swizzle: batch = blockIdx&7 -> each XCD keeps its batch's msg panel L2-hot.
//
// v6: glds + counted vmcnt. v4's VGPR_Count=88 proved the compiler collapses
// register-staged pipelines (4 named sets need >=112 VGPR); all register
// variants pinned at ~9.3 B/cyc/CU. Now staging is __builtin_amdgcn_global_load_lds
// (width 16): pipeline depth lives in the vmem queue -> uncollapsible. Per
// phase/wave 6 glds; s_waitcnt vmcnt(6) (counted, never 0 in-loop) keeps next
// tile's loads in flight across both barriers (T3/T4, m97/m218). LDS linear
// (glds dest = wave-uniform base + lane*16) with both-sides XOR swizzle
// (rule 21): global source col-chunk = c ^ (row&7), same involution on the
// ds_read side -> bank conflicts <=4-8-way instead of 32-way.
// agg00's fp32 path + in-loop writeback removed (cvt pass handles it) ->
// all three agg dispatches identical structure, clean vmcnt counting.

typedef __bf16 bf16;
typedef __bf16 bf16x8 __attribute__((ext_vector_type(8)));
typedef float  f32x16 __attribute__((ext_vector_type(16)));
typedef float  f32x4  __attribute__((ext_vector_type(4)));

static __device__ inline f32x16 mfma32(bf16x8 a, bf16x8 b, f32x16 c) {
    return __builtin_amdgcn_mfma_f32_32x32x16_bf16(a, b, c, 0, 0, 0);
}

// async global->LDS, 16B per lane; lds dest is wave-uniform base + lane*16
static __device__ inline void glds16(const bf16* g, bf16* l) {
    __builtin_amdgcn_global_load_lds(
        (const __attribute__((address_space(1))) unsigned int*)g,
        (__attribute__((address_space(3))) unsigned int*)l, 16, 0, 0);
}

#define NB   8
#define NN   2048
#define LAT  64
#define HID  128
#define ODIM 64
#define BM   64    // rows per block
#define BK   128   // k per phase
#define NP   16    // phases (2048 / 128)
#define HLD  136   // Hs row stride

// ---------------- dispatch 1: transform0 + weight prep + adj convert ----------------
__global__ __launch_bounds__(256) void prep_t0_k(
    const float* __restrict__ lat, const float* __restrict__ adj,
    const float* __restrict__ W0, const float* __restrict__ b0,
    const float* __restrict__ W1, const float* __restrict__ W2,
    const float* __restrict__ Wout,
    bf16* __restrict__ msgT, bf16* __restrict__ adjb,
    bf16* __restrict__ WT1, bf16* __restrict__ WT2, bf16* __restrict__ WoutT)
{
    __shared__ __align__(16) bf16 WTs[HID * 72];   // W0^T [fo][k], stride 72
    int tid = threadIdx.x;
    int blk = blockIdx.x;

    if (blk >= 416) {           // adj fp32 -> bf16 stream (2048 blocks x 16384 floats)
        size_t base = (size_t)(blk - 416) * 16384;
        const float* s = adj + base;
        bf16* d = adjb + base;
#pragma unroll
        for (int j = 0; j < 8; ++j) {
            int off = j * 2048 + tid * 8;
            f32x4 x0 = *(const f32x4*)(s + off);
            f32x4 x1 = *(const f32x4*)(s + off + 4);
            bf16x8 v;
            v[0]=(bf16)x0[0]; v[1]=(bf16)x0[1]; v[2]=(bf16)x0[2]; v[3]=(bf16)x0[3];
            v[4]=(bf16)x1[0]; v[5]=(bf16)x1[1]; v[6]=(bf16)x1[2]; v[7]=(bf16)x1[3];
            *(bf16x8*)(d + off) = v;
        }
        return;
    }

    if (blk >= 256) {           // weight transposes (tiny)
        int i = (blk - 256) * 256 + tid;
        if (i < HID * HID) { int fo = i >> 7, k = i & 127; WT1[i] = (bf16)W1[k * HID + fo]; return; }
        i -= HID * HID;
        if (i < HID * HID) { int fo = i >> 7, k = i & 127; WT2[i] = (bf16)W2[k * HID + fo]; return; }
        i -= HID * HID;
        if (i < ODIM * HID) { int o = i >> 7, k = i & 127; WoutT[i] = (bf16)Wout[k * ODIM + o]; return; }
        return;
    }

    // stage W0^T into LDS (W0 is [64][128] row-major, coalesced fp32 reads)
    for (int i = tid; i < LAT * HID; i += 256) {
        int k = i >> 7, fo = i & 127;
        WTs[fo * 72 + k] = (bf16)W0[i];
    }
    __syncthreads();

    int l = tid & 63, w = tid >> 6;
    int lm = l & 31, lh = l >> 5;
    int g0 = blk * 64;
    int b  = g0 >> 11, nb = g0 & 2047;

    const bf16*  Wrow = &WTs[(w * 32 + lm) * 72 + lh * 8];
    const float* r0   = lat + (size_t)(g0 + lm) * LAT + lh * 8;
    const float* r1   = r0 + (size_t)32 * LAT;

    f32x16 acc0 = {}, acc1 = {};
#pragma unroll
    for (int k0 = 0; k0 < LAT; k0 += 16) {
        bf16x8 a = *(const bf16x8*)(Wrow + k0);
        f32x4 x0 = *(const f32x4*)(r0 + k0), x1 = *(const f32x4*)(r0 + k0 + 4);
        f32x4 y0 = *(const f32x4*)(r1 + k0), y1 = *(const f32x4*)(r1 + k0 + 4);
        bf16x8 v0, v1;
        v0[0]=(bf16)x0[0]; v0[1]=(bf16)x0[1]; v0[2]=(bf16)x0[2]; v0[3]=(bf16)x0[3];
        v0[4]=(bf16)x1[0]; v0[5]=(bf16)x1[1]; v0[6]=(bf16)x1[2]; v0[7]=(bf16)x1[3];
        v1[0]=(bf16)y0[0]; v1[1]=(bf16)y0[1]; v1[2]=(bf16)y0[2]; v1[3]=(bf16)y0[3];
        v1[4]=(bf16)y1[0]; v1[5]=(bf16)y1[1]; v1[6]=(bf16)y1[2]; v1[7]=(bf16)y1[3];
        acc0 = mfma32(a, v0, acc0);
        acc1 = mfma32(a, v1, acc1);
    }

    bf16* outb = msgT + (size_t)b * (HID * NN) + nb;
#pragma unroll
    for (int r = 0; r < 16; ++r) {
        int fo = w * 32 + (r & 3) + 8 * (r >> 2) + 4 * lh;
        float bv = b0[fo];
        outb[(size_t)fo * NN + lm]      = (bf16)(acc0[r] + bv);
        outb[(size_t)fo * NN + 32 + lm] = (bf16)(acc1[r] + bv);
    }
}

// ---------------- dispatches 2-4: fused aggregate (glds + counted vmcnt) ------------
// Block: 512 threads = 8 waves (wave grid 2m x 4n), output 64 rows x 128 feats.
template<int MODE>
__global__ __launch_bounds__(512) void agg_k(
    const bf16* __restrict__ adjb,
    const bf16* __restrict__ msgT, const bf16* __restrict__ WTn,
    const float* __restrict__ biasn, bf16* __restrict__ msg_out,
    const float* __restrict__ mask, float* __restrict__ out)
{
    __shared__ __align__(16) bf16 As[2][BM * BK];    // 32 KB, linear (glds dest)
    __shared__ __align__(16) bf16 Bs[2][HID * BK];   // 64 KB, linear (glds dest)
    __shared__ __align__(16) bf16 Hs[BM * HLD];      // 17.4 KB
    int tid = threadIdx.x;
    int l = tid & 63, wv = tid >> 6;
    int lm = l & 31, lh = l >> 5;
    int wm = wv >> 2, wn = wv & 3;      // wave grid: 2 (m) x 4 (n)
    int b  = blockIdx.x & 7;            // XCD swizzle: batch b -> XCD b
    int m0 = (blockIdx.x >> 3) * BM;

    int r4 = l >> 4, c16 = l & 15;      // glds lane mapping: lane -> (row r4, chunk c16)

    const bf16* adjbase = adjb + (size_t)b * NN * NN + (size_t)m0 * NN;
    const bf16* msgb    = msgT + (size_t)b * (HID * NN);

    // glds per-lane global sources; col chunk pre-swizzled c ^ (row&7) (involution,
    // same XOR applied on the ds_read side -> rule 21 both-sides swizzle).
    int ar0 = wv * 8 + r4, ar1 = ar0 + 4;               // A rows (2 glds/wave)
    const bf16* aS0 = adjbase + (size_t)ar0 * NN + ((c16 ^ (ar0 & 7)) * 8);
    const bf16* aS1 = adjbase + (size_t)ar1 * NN + ((c16 ^ (ar1 & 7)) * 8);
    int br0 = wv * 16 + r4;                             // B rows (4 glds/wave)
    const bf16* bS0 = msgb + (size_t)(br0     ) * NN + ((c16 ^ ((br0     ) & 7)) * 8);
    const bf16* bS1 = msgb + (size_t)(br0 +  4) * NN + ((c16 ^ ((br0 +  4) & 7)) * 8);
    const bf16* bS2 = msgb + (size_t)(br0 +  8) * NN + ((c16 ^ ((br0 +  8) & 7)) * 8);
    const bf16* bS3 = msgb + (size_t)(br0 + 12) * NN + ((c16 ^ ((br0 + 12) & 7)) * 8);

    auto stage = [&](int buf, int k) {   // 6 glds/wave; LDS dest wave-uniform
        glds16(aS0 + k, &As[buf][(wv * 8     ) * BK]);
        glds16(aS1 + k, &As[buf][(wv * 8 +  4) * BK]);
        glds16(bS0 + k, &Bs[buf][(wv * 16    ) * BK]);
        glds16(bS1 + k, &Bs[buf][(wv * 16 + 4) * BK]);
        glds16(bS2 + k, &Bs[buf][(wv * 16 + 8) * BK]);
        glds16(bS3 + k, &Bs[buf][(wv * 16 +12) * BK]);
    };

    f32x16 acc = {};
    auto mfmaTile = [&](int buf) {
        int arow = wm * 32 + lm;
        int brow = wn * 32 + lm;
        const bf16* Abase = &As[buf][arow * BK];
        const bf16* Bbase = &Bs[buf][brow * BK];
        int h = lm & 7;                  // arow&7 == brow&7 == lm&7
#pragma unroll
        for (int s = 0; s < 8; ++s) {
            int ca = ((lh + 2 * s) ^ h) * 8;
            acc = mfma32(*(const bf16x8*)(Abase + ca), *(const bf16x8*)(Bbase + ca), acc);
        }
    };

    // prologue: tiles 0,1 staged (12 glds/wave in flight)
    stage(0, 0);
    stage(1, BK);

#pragma unroll 1
    for (int t = 0; t < NP; ++t) {
        // counted wait: tile t's 6 glds landed; tile t+1's 6 stay in flight
        if (t < NP - 1) asm volatile("s_waitcnt vmcnt(6)" ::: "memory");
        else            asm volatile("s_waitcnt vmcnt(0)" ::: "memory");
        __builtin_amdgcn_s_barrier();
        mfmaTile(t & 1);
        asm volatile("" ::: "memory");   // pin ds_reads/glds across the barrier
        __builtin_amdgcn_s_barrier();
        if (t + 2 < NP) stage(t & 1, (t + 2) * BK);
    }

    // relu(h) -> LDS [node][feat]; node = wm*32 + crow(r), feat = wn*32 + lm
#pragma unroll
    for (int r = 0; r < 16; ++r) {
        int row = wm * 32 + (r & 3) + 8 * (r >> 2) + 4 * lh;
        float v = acc[r];
        Hs[row * HLD + wn * 32 + lm] = (bf16)(v > 0.f ? v : 0.f);
    }
    __syncthreads();

    if (MODE == 0) {
        // msg_out[fo][m0+node] = WTn[fo][:] . h[node][:] + biasn[fo]
        const bf16* Arow = WTn + (size_t)(wn * 32 + lm) * HID + lh * 8;
        const bf16* Brow = &Hs[(wm * 32 + lm) * HLD + lh * 8];
        f32x16 acc2 = {};
#pragma unroll
        for (int s = 0; s < 8; ++s)
            acc2 = mfma32(*(const bf16x8*)(Arow + s * 16), *(const bf16x8*)(Brow + s * 16), acc2);
        bf16* outb = msg_out + (size_t)b * (HID * NN) + m0 + wm * 32;
#pragma unroll
        for (int r = 0; r < 16; ++r) {
            int fo = wn * 32 + (r & 3) + 8 * (r >> 2) + 4 * lh;
            outb[(size_t)fo * NN + lm] = (bf16)(acc2[r] + biasn[fo]);
        }
    } else {
        if (wn < 2) {
            int ob = wn * 32;
            const bf16* Arow = &Hs[(wm * 32 + lm) * HLD + lh * 8];
            const bf16* Brow = WTn + (size_t)(ob + lm) * HID + lh * 8;
            f32x16 acc2 = {};
#pragma unroll
            for (int s = 0; s < 8; ++s)
                acc2 = mfma32(*(const bf16x8*)(Arow + s * 16), *(const bf16x8*)(Brow + s * 16), acc2);
            float bv = biasn[ob + lm];
#pragma unroll
            for (int r = 0; r < 16; ++r) {
                int node = wm * 32 + (r & 3) + 8 * (r >> 2) + 4 * lh;
                int g = b * NN + m0 + node;
                out[(size_t)g * ODIM + ob + lm] = (acc2[r] + bv) * mask[g];
            }
        }
    }
}

extern "C" void kernel_launch(void* const* d_in, const int* in_sizes, int n_in,
                              void* d_out, int out_size, void* d_ws, size_t ws_size,
                              hipStream_t stream)
{
    const float* lat  = (const float*)d_in[0];
    const float* adj  = (const float*)d_in[1];
    const float* mask = (const float*)d_in[2];
    const float* W0   = (const float*)d_in[3];
    const float* b0   = (const float*)d_in[4];
    const float* W1   = (const float*)d_in[5];
    const float* b1   = (const float*)d_in[6];
    const float* W2   = (const float*)d_in[7];
    const float* b2   = (const float*)d_in[8];
    const float* Wout = (const float*)d_in[9];
    const float* bout = (const float*)d_in[10];
    float* out = (float*)d_out;

    char* ws = (char*)d_ws;
    bf16* msgA  = (bf16*)(ws + 0);            // 4 MiB
    bf16* msgB  = (bf16*)(ws + 4194304);      // 4 MiB
    bf16* adjbf = (bf16*)(ws + 8388608);      // 8*2048*2048*2 = 64 MiB
    bf16* WT1   = (bf16*)(ws + 75497472);     // 32 KiB
    bf16* WT2   = (bf16*)(ws + 75530240);     // 32 KiB
    bf16* WoutT = (bf16*)(ws + 75563008);     // 16 KiB

    // blocks 0-255: transform0; 256-415: weight transposes; 416-2463: adj cvt
    prep_t0_k<<<2464, 256, 0, stream>>>(lat, adj, W0, b0, W1, W2, Wout,
                                        msgA, adjbf, WT1, WT2, WoutT);

    // 256 blocks = 32 m-tiles x 8 batches, 1 block/CU
    agg_k<0><<<256, 512, 0, stream>>>(adjbf, msgA, WT1, b1, msgB, nullptr, nullptr);
    agg_k<0><<<256, 512, 0, stream>>>(adjbf, msgB, WT2, b2, msgA, nullptr, nullptr);
    agg_k<1><<<256, 512, 0, stream>>>(adjbf, msgA, WoutT, bout, nullptr, mask, out);
}

// Round 6
// 278.682 us; speedup vs baseline: 1.0653x; 1.0653x over previous
//
#include <hip/hip_runtime.h>
#include <hip/hip_bf16.h>

// GCN decoder, 4 dispatches:
//  1) prep_t0_k: blocks 0-255 compute msg0 = lat@W0+b0 (W0 transposed via LDS);
//     blocks 256+ transpose W1/W2/Wout to bf16 [fo][k].
//  2) agg_k<0,0> (v5 register-staged): h1 = relu(adj_fp32@msg0) with fused
//     bf16-adj writeback + epilogue transform (msg1 = h1@W1+b1).
//  3-4) aggg_k<MODE> (v6 glds + counted vmcnt): consume the bf16 adj copy.
//       MODE=0: epilogue transform (msg2). MODE=1: output proj * mask.
// XCD swizzle: batch = blockIdx&7 -> each XCD keeps its batch's msg panel L2-hot.
//
// v7: recombination of v5 (best total, 267.8) and v6 along kernel boundaries.
// v6's accounting showed the standalone fp32->bf16 pass cost ~32us of pure
// streaming at the same ~10 B/cyc/CU cap agg00 runs at -> net loss. But its
// glds agg kernels passed and may sit at the byte floor (~33us). So: agg00
// reverts to v5's fused reg-staged form (produces adjbf in-loop), and the two
// bf16 aggregations keep v6's glds structure. Disjoint change -> the total
// delta vs v5 cleanly isolates glds-vs-regstage for agg01/agg11.

typedef __bf16 bf16;
typedef __bf16 bf16x4 __attribute__((ext_vector_type(4)));
typedef __bf16 bf16x8 __attribute__((ext_vector_type(8)));
typedef float  f32x16 __attribute__((ext_vector_type(16)));
typedef float  f32x4  __attribute__((ext_vector_type(4)));

static __device__ inline f32x16 mfma32(bf16x8 a, bf16x8 b, f32x16 c) {
    return __builtin_amdgcn_mfma_f32_32x32x16_bf16(a, b, c, 0, 0, 0);
}

// Barrier that does NOT drain vmcnt: LDS stores must be complete (lgkmcnt 0),
// but global prefetch loads stay in flight.
static __device__ inline void tile_barrier() {
    asm volatile("s_waitcnt lgkmcnt(0)" ::: "memory");
    __builtin_amdgcn_s_barrier();
    asm volatile("" ::: "memory");
}

// async global->LDS, 16B per lane; lds dest is wave-uniform base + lane*16
static __device__ inline void glds16(const bf16* g, bf16* l) {
    __builtin_amdgcn_global_load_lds(
        (const __attribute__((address_space(1))) unsigned int*)g,
        (__attribute__((address_space(3))) unsigned int*)l, 16, 0, 0);
}

#define NB   8
#define NN   2048
#define LAT  64
#define HID  128
#define ODIM 64
#define BM   64    // rows per block
#define BK   128   // k per phase
#define NP   16    // phases (2048 / 128)
#define LDK  136   // padded LDS row stride (v5 reg-staged kernel)
#define HLD  136   // Hs row stride

// ---------------- dispatch 1: transform0 (blocks 0-255) + weight prep (blocks 256+) ----
__global__ __launch_bounds__(256) void prep_t0_k(
    const float* __restrict__ lat, const float* __restrict__ W0,
    const float* __restrict__ b0,
    const float* __restrict__ W1, const float* __restrict__ W2,
    const float* __restrict__ Wout,
    bf16* __restrict__ msgT, bf16* __restrict__ WT1,
    bf16* __restrict__ WT2, bf16* __restrict__ WoutT)
{
    __shared__ __align__(16) bf16 WTs[HID * 72];   // W0^T [fo][k], stride 72
    int tid = threadIdx.x;
    int blk = blockIdx.x;

    if (blk >= 256) {           // weight transposes (tiny)
        int i = (blk - 256) * 256 + tid;
        if (i < HID * HID) { int fo = i >> 7, k = i & 127; WT1[i] = (bf16)W1[k * HID + fo]; return; }
        i -= HID * HID;
        if (i < HID * HID) { int fo = i >> 7, k = i & 127; WT2[i] = (bf16)W2[k * HID + fo]; return; }
        i -= HID * HID;
        if (i < ODIM * HID) { int o = i >> 7, k = i & 127; WoutT[i] = (bf16)Wout[k * ODIM + o]; return; }
        return;
    }

    // stage W0^T into LDS (W0 is [64][128] row-major, coalesced fp32 reads)
    for (int i = tid; i < LAT * HID; i += 256) {
        int k = i >> 7, fo = i & 127;
        WTs[fo * 72 + k] = (bf16)W0[i];
    }
    __syncthreads();

    int l = tid & 63, w = tid >> 6;
    int lm = l & 31, lh = l >> 5;
    int g0 = blk * 64;
    int b  = g0 >> 11, nb = g0 & 2047;

    const bf16*  Wrow = &WTs[(w * 32 + lm) * 72 + lh * 8];
    const float* r0   = lat + (size_t)(g0 + lm) * LAT + lh * 8;
    const float* r1   = r0 + (size_t)32 * LAT;

    f32x16 acc0 = {}, acc1 = {};
#pragma unroll
    for (int k0 = 0; k0 < LAT; k0 += 16) {
        bf16x8 a = *(const bf16x8*)(Wrow + k0);
        f32x4 x0 = *(const f32x4*)(r0 + k0), x1 = *(const f32x4*)(r0 + k0 + 4);
        f32x4 y0 = *(const f32x4*)(r1 + k0), y1 = *(const f32x4*)(r1 + k0 + 4);
        bf16x8 v0, v1;
        v0[0]=(bf16)x0[0]; v0[1]=(bf16)x0[1]; v0[2]=(bf16)x0[2]; v0[3]=(bf16)x0[3];
        v0[4]=(bf16)x1[0]; v0[5]=(bf16)x1[1]; v0[6]=(bf16)x1[2]; v0[7]=(bf16)x1[3];
        v1[0]=(bf16)y0[0]; v1[1]=(bf16)y0[1]; v1[2]=(bf16)y0[2]; v1[3]=(bf16)y0[3];
        v1[4]=(bf16)y1[0]; v1[5]=(bf16)y1[1]; v1[6]=(bf16)y1[2]; v1[7]=(bf16)y1[3];
        acc0 = mfma32(a, v0, acc0);
        acc1 = mfma32(a, v1, acc1);
    }

    bf16* outb = msgT + (size_t)b * (HID * NN) + nb;
#pragma unroll
    for (int r = 0; r < 16; ++r) {
        int fo = w * 32 + (r & 3) + 8 * (r >> 2) + 4 * lh;
        float bv = b0[fo];
        outb[(size_t)fo * NN + lm]      = (bf16)(acc0[r] + bv);
        outb[(size_t)fo * NN + 32 + lm] = (bf16)(acc1[r] + bv);
    }
}

// ---------------- dispatch 2: fused aggregate, fp32 adj + writeback (v5) -----------
// Block: 512 threads = 8 waves (wave grid 2m x 4n), output 64 rows x 128 feats.
__global__ __launch_bounds__(512) void agg_f32_k(
    const float* __restrict__ adjf, bf16* __restrict__ adjbo,
    const bf16* __restrict__ msgT, const bf16* __restrict__ WTn,
    const float* __restrict__ biasn, bf16* __restrict__ msg_out)
{
    __shared__ __align__(16) bf16 As[2][BM * LDK];    // 34.8 KB
    __shared__ __align__(16) bf16 Bs[2][HID * LDK];   // 69.6 KB
    __shared__ __align__(16) bf16 Hs[BM * HLD];       // 17.4 KB
    int tid = threadIdx.x;
    int l = tid & 63, w = tid >> 6;
    int lm = l & 31, lh = l >> 5;
    int wm = w >> 2, wn = w & 3;        // wave grid: 2 (m) x 4 (n)
    int b  = blockIdx.x & 7;            // XCD swizzle: batch b -> XCD b
    int m0 = (blockIdx.x >> 3) * BM;

    const bf16* msgb = msgT + (size_t)b * (HID * NN);
    int br = tid >> 3, bc8 = (tid & 7) * 8;
    const bf16* bsrc = msgb + (size_t)br * NN + bc8;

    int ar = tid >> 3, acf = (tid & 7) * 4;
    const float* asrc = adjf  + (size_t)b * NN * NN + (size_t)(m0 + ar) * NN + acf;
    bf16*        adst = adjbo + (size_t)b * NN * NN + (size_t)(m0 + ar) * NN + acf;

    f32x4  fa[2][4];
    bf16x8 pb[2][4];

    auto loadTile = [&](int set, int k) {
#pragma unroll
        for (int g = 0; g < 4; ++g) fa[set][g] = *(const f32x4*)(asrc + k + g * 32);
#pragma unroll
        for (int h = 0; h < 2; ++h)
#pragma unroll
            for (int g = 0; g < 2; ++g)
                pb[set][h * 2 + g] = *(const bf16x8*)(bsrc + (size_t)(h * 64) * NN + k + g * 64);
    };
    auto storeTile = [&](int set, int buf, int k) {
#pragma unroll
        for (int g = 0; g < 4; ++g) {
            bf16x4 v;
            v[0]=(bf16)fa[set][g][0]; v[1]=(bf16)fa[set][g][1];
            v[2]=(bf16)fa[set][g][2]; v[3]=(bf16)fa[set][g][3];
            *(bf16x4*)&As[buf][ar * LDK + acf + g * 32] = v;
            *(bf16x4*)(adst + k + g * 32)               = v;   // bf16 adj writeback
        }
#pragma unroll
        for (int h = 0; h < 2; ++h)
#pragma unroll
            for (int g = 0; g < 2; ++g)
                *(bf16x8*)&Bs[buf][(br + h * 64) * LDK + bc8 + g * 64] = pb[set][h * 2 + g];
    };

    f32x16 acc = {};
    auto mfmaTile = [&](int buf) {
        const bf16* Ac = &As[buf][(wm * 32 + lm) * LDK + lh * 8];
        const bf16* Bc = &Bs[buf][(wn * 32 + lm) * LDK + lh * 8];
#pragma unroll
        for (int s = 0; s < 8; ++s)
            acc = mfma32(*(const bf16x8*)(Ac + s * 16), *(const bf16x8*)(Bc + s * 16), acc);
    };

    loadTile(0, 0 * BK);
    loadTile(1, 1 * BK);
    storeTile(0, 0, 0 * BK);
    tile_barrier();

#define PHASE(U)                                                               \
    do {                                                                       \
        int q = qb + (U);                                                      \
        if (q + 2 < NP) loadTile((U), (q + 2) * BK);                           \
        if (q + 1 < NP) storeTile(((U) + 1) & 1, ((U) + 1) & 1, (q + 1) * BK); \
        mfmaTile((U) & 1);                                                     \
        tile_barrier();                                                        \
    } while (0)

#pragma unroll 1
    for (int qb = 0; qb < NP; qb += 2) {
        PHASE(0);
        PHASE(1);
    }
#undef PHASE

    // relu(h) -> LDS [node][feat]
#pragma unroll
    for (int r = 0; r < 16; ++r) {
        int row = wm * 32 + (r & 3) + 8 * (r >> 2) + 4 * lh;
        float v = acc[r];
        Hs[row * HLD + wn * 32 + lm] = (bf16)(v > 0.f ? v : 0.f);
    }
    __syncthreads();

    // epilogue transform: msg_out[fo][m0+node] = WTn[fo][:] . h[node][:] + biasn[fo]
    const bf16* Arow = WTn + (size_t)(wn * 32 + lm) * HID + lh * 8;
    const bf16* Brow = &Hs[(wm * 32 + lm) * HLD + lh * 8];
    f32x16 acc2 = {};
#pragma unroll
    for (int s = 0; s < 8; ++s)
        acc2 = mfma32(*(const bf16x8*)(Arow + s * 16), *(const bf16x8*)(Brow + s * 16), acc2);
    bf16* outb = msg_out + (size_t)b * (HID * NN) + m0 + wm * 32;
#pragma unroll
    for (int r = 0; r < 16; ++r) {
        int fo = wn * 32 + (r & 3) + 8 * (r >> 2) + 4 * lh;
        outb[(size_t)fo * NN + lm] = (bf16)(acc2[r] + biasn[fo]);
    }
}

// ---------------- dispatches 3-4: fused aggregate, glds + counted vmcnt (v6) -------
template<int MODE>
__global__ __launch_bounds__(512) void aggg_k(
    const bf16* __restrict__ adjb,
    const bf16* __restrict__ msgT, const bf16* __restrict__ WTn,
    const float* __restrict__ biasn, bf16* __restrict__ msg_out,
    const float* __restrict__ mask, float* __restrict__ out)
{
    __shared__ __align__(16) bf16 As[2][BM * BK];    // 32 KB, linear (glds dest)
    __shared__ __align__(16) bf16 Bs[2][HID * BK];   // 64 KB, linear (glds dest)
    __shared__ __align__(16) bf16 Hs[BM * HLD];      // 17.4 KB
    int tid = threadIdx.x;
    int l = tid & 63, wv = tid >> 6;
    int lm = l & 31, lh = l >> 5;
    int wm = wv >> 2, wn = wv & 3;      // wave grid: 2 (m) x 4 (n)
    int b  = blockIdx.x & 7;            // XCD swizzle: batch b -> XCD b
    int m0 = (blockIdx.x >> 3) * BM;

    int r4 = l >> 4, c16 = l & 15;      // glds lane mapping: lane -> (row r4, chunk c16)

    const bf16* adjbase = adjb + (size_t)b * NN * NN + (size_t)m0 * NN;
    const bf16* msgb    = msgT + (size_t)b * (HID * NN);

    // glds per-lane global sources; col chunk pre-swizzled c ^ (row&7)
    int ar0 = wv * 8 + r4, ar1 = ar0 + 4;
    const bf16* aS0 = adjbase + (size_t)ar0 * NN + ((c16 ^ (ar0 & 7)) * 8);
    const bf16* aS1 = adjbase + (size_t)ar1 * NN + ((c16 ^ (ar1 & 7)) * 8);
    int br0 = wv * 16 + r4;
    const bf16* bS0 = msgb + (size_t)(br0     ) * NN + ((c16 ^ ((br0     ) & 7)) * 8);
    const bf16* bS1 = msgb + (size_t)(br0 +  4) * NN + ((c16 ^ ((br0 +  4) & 7)) * 8);
    const bf16* bS2 = msgb + (size_t)(br0 +  8) * NN + ((c16 ^ ((br0 +  8) & 7)) * 8);
    const bf16* bS3 = msgb + (size_t)(br0 + 12) * NN + ((c16 ^ ((br0 + 12) & 7)) * 8);

    auto stage = [&](int buf, int k) {   // 6 glds/wave; LDS dest wave-uniform
        glds16(aS0 + k, &As[buf][(wv * 8     ) * BK]);
        glds16(aS1 + k, &As[buf][(wv * 8 +  4) * BK]);
        glds16(bS0 + k, &Bs[buf][(wv * 16    ) * BK]);
        glds16(bS1 + k, &Bs[buf][(wv * 16 + 4) * BK]);
        glds16(bS2 + k, &Bs[buf][(wv * 16 + 8) * BK]);
        glds16(bS3 + k, &Bs[buf][(wv * 16 +12) * BK]);
    };

    f32x16 acc = {};
    auto mfmaTile = [&](int buf) {
        int arow = wm * 32 + lm;
        int brow = wn * 32 + lm;
        const bf16* Abase = &As[buf][arow * BK];
        const bf16* Bbase = &Bs[buf][brow * BK];
        int h = lm & 7;                  // arow&7 == brow&7 == lm&7
#pragma unroll
        for (int s = 0; s < 8; ++s) {
            int ca = ((lh + 2 * s) ^ h) * 8;
            acc = mfma32(*(const bf16x8*)(Abase + ca), *(const bf16x8*)(Bbase + ca), acc);
        }
    };

    stage(0, 0);
    stage(1, BK);

#pragma unroll 1
    for (int t = 0; t < NP; ++t) {
        if (t < NP - 1) asm volatile("s_waitcnt vmcnt(6)" ::: "memory");
        else            asm volatile("s_waitcnt vmcnt(0)" ::: "memory");
        __builtin_amdgcn_s_barrier();
        mfmaTile(t & 1);
        asm volatile("" ::: "memory");
        __builtin_amdgcn_s_barrier();
        if (t + 2 < NP) stage(t & 1, (t + 2) * BK);
    }

    // relu(h) -> LDS [node][feat]
#pragma unroll
    for (int r = 0; r < 16; ++r) {
        int row = wm * 32 + (r & 3) + 8 * (r >> 2) + 4 * lh;
        float v = acc[r];
        Hs[row * HLD + wn * 32 + lm] = (bf16)(v > 0.f ? v : 0.f);
    }
    __syncthreads();

    if (MODE == 0) {
        const bf16* Arow = WTn + (size_t)(wn * 32 + lm) * HID + lh * 8;
        const bf16* Brow = &Hs[(wm * 32 + lm) * HLD + lh * 8];
        f32x16 acc2 = {};
#pragma unroll
        for (int s = 0; s < 8; ++s)
            acc2 = mfma32(*(const bf16x8*)(Arow + s * 16), *(const bf16x8*)(Brow + s * 16), acc2);
        bf16* outb = msg_out + (size_t)b * (HID * NN) + m0 + wm * 32;
#pragma unroll
        for (int r = 0; r < 16; ++r) {
            int fo = wn * 32 + (r & 3) + 8 * (r >> 2) + 4 * lh;
            outb[(size_t)fo * NN + lm] = (bf16)(acc2[r] + biasn[fo]);
        }
    } else {
        if (wn < 2) {
            int ob = wn * 32;
            const bf16* Arow = &Hs[(wm * 32 + lm) * HLD + lh * 8];
            const bf16* Brow = WTn + (size_t)(ob + lm) * HID + lh * 8;
            f32x16 acc2 = {};
#pragma unroll
            for (int s = 0; s < 8; ++s)
                acc2 = mfma32(*(const bf16x8*)(Arow + s * 16), *(const bf16x8*)(Brow + s * 16), acc2);
            float bv = biasn[ob + lm];
#pragma unroll
            for (int r = 0; r < 16; ++r) {
                int node = wm * 32 + (r & 3) + 8 * (r >> 2) + 4 * lh;
                int g = b * NN + m0 + node;
                out[(size_t)g * ODIM + ob + lm] = (acc2[r] + bv) * mask[g];
            }
        }
    }
}

extern "C" void kernel_launch(void* const* d_in, const int* in_sizes, int n_in,
                              void* d_out, int out_size, void* d_ws, size_t ws_size,
                              hipStream_t stream)
{
    const float* lat  = (const float*)d_in[0];
    const float* adj  = (const float*)d_in[1];
    const float* mask = (const float*)d_in[2];
    const float* W0   = (const float*)d_in[3];
    const float* b0   = (const float*)d_in[4];
    const float* W1   = (const float*)d_in[5];
    const float* b1   = (const float*)d_in[6];
    const float* W2   = (const float*)d_in[7];
    const float* b2   = (const float*)d_in[8];
    const float* Wout = (const float*)d_in[9];
    const float* bout = (const float*)d_in[10];
    float* out = (float*)d_out;

    char* ws = (char*)d_ws;
    bf16* msgA  = (bf16*)(ws + 0);            // 4 MiB
    bf16* msgB  = (bf16*)(ws + 4194304);      // 4 MiB
    bf16* adjbf = (bf16*)(ws + 8388608);      // 8*2048*2048*2 = 64 MiB
    bf16* WT1   = (bf16*)(ws + 75497472);     // 32 KiB
    bf16* WT2   = (bf16*)(ws + 75530240);     // 32 KiB
    bf16* WoutT = (bf16*)(ws + 75563008);     // 16 KiB

    // blocks 0-255: transform0; blocks 256-415: weight transposes (40960 elems)
    prep_t0_k<<<416, 256, 0, stream>>>(lat, W0, b0, W1, W2, Wout, msgA, WT1, WT2, WoutT);

    // 256 blocks = 32 m-tiles x 8 batches, 1 block/CU
    agg_f32_k<<<256, 512, 0, stream>>>(adj, adjbf, msgA, WT1, b1, msgB);
    aggg_k<0><<<256, 512, 0, stream>>>(adjbf, msgB, WT2, b2, msgA, nullptr, nullptr);
    aggg_k<1><<<256, 512, 0, stream>>>(adjbf, msgA, WoutT, bout, nullptr, mask, out);
}